// Round 7
// baseline (431.794 us; speedup 1.0000x reference)
//
#include <hip/hip_runtime.h>
#include <hip/hip_bf16.h>
#include <math.h>

#define B_ 4
#define S_ 1024
#define D_ 1024
#define H_ 16
#define HD_ 64

typedef __hip_bfloat16 bf16_t;
typedef __attribute__((ext_vector_type(8))) short bf16x8;
typedef __attribute__((ext_vector_type(4))) float floatx4;

__device__ __forceinline__ float bf2f(ushort u) {
  return __uint_as_float((unsigned)u << 16);
}

// ---------------- LayerNorm: fp32 in, bf16 out. One block per row. ----------
__global__ __launch_bounds__(256) void ln_kernel(const float* __restrict__ x,
                                                 const float* __restrict__ scale,
                                                 const float* __restrict__ shift,
                                                 bf16_t* __restrict__ out) {
  const int row = blockIdx.x;
  const float* xr = x + (size_t)row * D_;
  float4 v = ((const float4*)xr)[threadIdx.x];  // 256 threads * 4 = 1024
  float s = v.x + v.y + v.z + v.w;
  float ss = v.x * v.x + v.y * v.y + v.z * v.z + v.w * v.w;
#pragma unroll
  for (int off = 32; off > 0; off >>= 1) {
    s += __shfl_xor(s, off);
    ss += __shfl_xor(ss, off);
  }
  __shared__ float ls[4], lss[4];
  __shared__ float stats[2];
  const int wave = threadIdx.x >> 6, lane = threadIdx.x & 63;
  if (lane == 0) { ls[wave] = s; lss[wave] = ss; }
  __syncthreads();
  if (threadIdx.x == 0) {
    float t = ls[0] + ls[1] + ls[2] + ls[3];
    float tt = lss[0] + lss[1] + lss[2] + lss[3];
    float mean = t * (1.0f / D_);
    float var = tt * (1.0f / D_) - mean * mean;
    stats[0] = mean;
    stats[1] = rsqrtf(var + 1e-5f);
  }
  __syncthreads();
  const float mean = stats[0], rstd = stats[1];
  float4 sc = ((const float4*)scale)[threadIdx.x];
  float4 sh = ((const float4*)shift)[threadIdx.x];
  bf16_t ob[4];
  ob[0] = __float2bfloat16(sc.x * (v.x - mean) * rstd + sh.x);
  ob[1] = __float2bfloat16(sc.y * (v.y - mean) * rstd + sh.y);
  ob[2] = __float2bfloat16(sc.z * (v.z - mean) * rstd + sh.z);
  ob[3] = __float2bfloat16(sc.w * (v.w - mean) * rstd + sh.w);
  *(ushort4*)(out + (size_t)row * D_ + threadIdx.x * 4) = *(ushort4*)ob;
}

// ------------- Weight convert + transpose: W fp32 [K,N] -> Wt bf16 [N,K] ----
__global__ __launch_bounds__(256) void convt_kernel(const float* __restrict__ W,
                                                    bf16_t* __restrict__ Wt,
                                                    int K, int N) {
  __shared__ float t[32][33];
  const int n0 = blockIdx.x * 32, k0 = blockIdx.y * 32;
  const int lx = threadIdx.x & 31, ly = threadIdx.x >> 5;  // 32 x 8
#pragma unroll
  for (int r = ly; r < 32; r += 8) t[r][lx] = W[(size_t)(k0 + r) * N + n0 + lx];
  __syncthreads();
#pragma unroll
  for (int r = ly; r < 32; r += 8)
    Wt[(size_t)(n0 + r) * K + k0 + lx] = __float2bfloat16(t[lx][r]);
}

// ------------- bf16 MFMA GEMM (m97 structure + XOR-swizzled LDS) ------------
// A [M,K] bf16 row-major, Bt [N,K] bf16 row-major. 128x128 tile, BK=32,
// 256 threads = 4 waves in 2x2, each wave 64x64 via 4x4 MFMA 16x16x32.
// LDS swizzle: staging lane fetches global 16B chunk (co ^ (ro&3)) of its
// 64B row; fragment reads use chunk (quad ^ (fr&3)). Balances every
// ds_read_b128 to 8 lanes per 4-bank group (was 16) -> no extra conflict
// cycles. Global coalescing unchanged (permutation within 64B segment).
// mode 0: C bf16 | 1: bias+gelu -> C bf16 | 2: bias + R(fp32) -> C fp32
// mode 4: bf16 partial -> ((bf16*)C) + z*M*N   (split-K)
__global__ __launch_bounds__(256) void mgemm_kernel(const bf16_t* __restrict__ A,
                                                    const bf16_t* __restrict__ Bt,
                                                    const float* __restrict__ bias,
                                                    const float* __restrict__ R,
                                                    void* __restrict__ C,
                                                    int M, int N, int K, int Kc,
                                                    int mode) {
  __shared__ bf16_t As[128 * 32];
  __shared__ bf16_t Bs[128 * 32];
  const int tid = threadIdx.x;
  const int lane = tid & 63, w = tid >> 6;
  const int m0 = blockIdx.y * 128, n0 = blockIdx.x * 128;
  const int kz0 = blockIdx.z * Kc;
  const int wm = (w >> 1) * 64, wn = (w & 1) * 64;

  floatx4 zero = {0.f, 0.f, 0.f, 0.f};
  floatx4 acc[4][4];
#pragma unroll
  for (int i = 0; i < 4; i++)
#pragma unroll
    for (int j = 0; j < 4; j++) acc[i][j] = zero;

  const int ro = lane >> 2;             // row within 16-row chunk block
  const int cs = (lane & 3) ^ (ro & 3); // swizzled source 16B-chunk
  const int co = cs * 8;                // element offset
  const bf16_t* ga0 = A + (size_t)(m0 + w * 16 + ro) * K + co;
  const bf16_t* ga1 = A + (size_t)(m0 + (w + 4) * 16 + ro) * K + co;
  const bf16_t* gb0 = Bt + (size_t)(n0 + w * 16 + ro) * K + co;
  const bf16_t* gb1 = Bt + (size_t)(n0 + (w + 4) * 16 + ro) * K + co;
  bf16_t* la0 = &As[(w) * 512];
  bf16_t* la1 = &As[(w + 4) * 512];
  bf16_t* lb0 = &Bs[(w) * 512];
  bf16_t* lb1 = &Bs[(w + 4) * 512];

  const int fr = lane & 15, quad = lane >> 4;
  const int sq = (quad ^ (fr & 3)) * 8;  // swizzled fragment k-offset

  for (int k0 = kz0; k0 < kz0 + Kc; k0 += 32) {
    __syncthreads();
    __builtin_amdgcn_global_load_lds(
        (const __attribute__((address_space(1))) void*)(ga0 + k0),
        (__attribute__((address_space(3))) void*)la0, 16, 0, 0);
    __builtin_amdgcn_global_load_lds(
        (const __attribute__((address_space(1))) void*)(ga1 + k0),
        (__attribute__((address_space(3))) void*)la1, 16, 0, 0);
    __builtin_amdgcn_global_load_lds(
        (const __attribute__((address_space(1))) void*)(gb0 + k0),
        (__attribute__((address_space(3))) void*)lb0, 16, 0, 0);
    __builtin_amdgcn_global_load_lds(
        (const __attribute__((address_space(1))) void*)(gb1 + k0),
        (__attribute__((address_space(3))) void*)lb1, 16, 0, 0);
    __syncthreads();

    bf16x8 af[4], bfr[4];
#pragma unroll
    for (int i = 0; i < 4; i++) {
      af[i] = *(const bf16x8*)&As[(wm + i * 16 + fr) * 32 + sq];
      bfr[i] = *(const bf16x8*)&Bs[(wn + i * 16 + fr) * 32 + sq];
    }
#pragma unroll
    for (int i = 0; i < 4; i++)
#pragma unroll
      for (int j = 0; j < 4; j++)
        acc[i][j] = __builtin_amdgcn_mfma_f32_16x16x32_bf16(af[i], bfr[j],
                                                            acc[i][j], 0, 0, 0);
  }

  // epilogue: C/D layout col=lane&15, row=quad*4+reg
  bf16_t* Pz = (mode == 4)
                   ? ((bf16_t*)C + (size_t)blockIdx.z * M * N)
                   : nullptr;
#pragma unroll
  for (int j = 0; j < 4; j++) {
    const int col = n0 + wn + j * 16 + fr;
    const float bj = bias ? bias[col] : 0.f;
#pragma unroll
    for (int i = 0; i < 4; i++) {
      const int rbase = m0 + wm + i * 16 + quad * 4;
#pragma unroll
      for (int r = 0; r < 4; r++) {
        const int row = rbase + r;
        float c = acc[i][j][r] + bj;
        if (mode == 1) {  // gelu(tanh) via fast sigmoid
          const float xg = c;
          const float t = 0.7978845608028654f * (xg + 0.044715f * xg * xg * xg);
          const float th = 2.0f / (1.0f + __expf(-2.0f * t)) - 1.0f;
          c = 0.5f * xg * (1.0f + th);
        }
        if (mode == 4) {
          Pz[(size_t)row * N + col] = __float2bfloat16(c);
        } else if (mode == 2) {
          c += R[(size_t)row * N + col];
          ((float*)C)[(size_t)row * N + col] = c;
        } else {
          ((bf16_t*)C)[(size_t)row * N + col] = __float2bfloat16(c);
        }
      }
    }
  }
}

// --- fused: out = x + P0 + P1 + bias ; h = LN2(out). One block per row. -----
__global__ __launch_bounds__(256) void reduce2_ln_kernel(
    const bf16_t* __restrict__ P, size_t slice, const float* __restrict__ x,
    const float* __restrict__ bias, const float* __restrict__ scale,
    const float* __restrict__ shift, float* __restrict__ out,
    bf16_t* __restrict__ h) {
  const int row = blockIdx.x;
  const size_t e = (size_t)row * D_ + threadIdx.x * 4;
  const float4 xv = *(const float4*)(x + e);
  const ushort4 p0 = *(const ushort4*)((const ushort*)P + e);
  const ushort4 p1 = *(const ushort4*)((const ushort*)P + slice + e);
  const float4 bb = *(const float4*)(bias + threadIdx.x * 4);
  float4 v;
  v.x = xv.x + bf2f(p0.x) + bf2f(p1.x) + bb.x;
  v.y = xv.y + bf2f(p0.y) + bf2f(p1.y) + bb.y;
  v.z = xv.z + bf2f(p0.z) + bf2f(p1.z) + bb.z;
  v.w = xv.w + bf2f(p0.w) + bf2f(p1.w) + bb.w;
  *(float4*)(out + e) = v;

  float s = v.x + v.y + v.z + v.w;
  float ss = v.x * v.x + v.y * v.y + v.z * v.z + v.w * v.w;
#pragma unroll
  for (int off = 32; off > 0; off >>= 1) {
    s += __shfl_xor(s, off);
    ss += __shfl_xor(ss, off);
  }
  __shared__ float ls[4], lss[4];
  __shared__ float stats[2];
  const int wave = threadIdx.x >> 6, lane = threadIdx.x & 63;
  if (lane == 0) { ls[wave] = s; lss[wave] = ss; }
  __syncthreads();
  if (threadIdx.x == 0) {
    float t = ls[0] + ls[1] + ls[2] + ls[3];
    float tt = lss[0] + lss[1] + lss[2] + lss[3];
    float mean = t * (1.0f / D_);
    float var = tt * (1.0f / D_) - mean * mean;
    stats[0] = mean;
    stats[1] = rsqrtf(var + 1e-5f);
  }
  __syncthreads();
  const float mean = stats[0], rstd = stats[1];
  const float4 sc = *(const float4*)(scale + threadIdx.x * 4);
  const float4 sh = *(const float4*)(shift + threadIdx.x * 4);
  bf16_t ob[4];
  ob[0] = __float2bfloat16(sc.x * (v.x - mean) * rstd + sh.x);
  ob[1] = __float2bfloat16(sc.y * (v.y - mean) * rstd + sh.y);
  ob[2] = __float2bfloat16(sc.z * (v.z - mean) * rstd + sh.z);
  ob[3] = __float2bfloat16(sc.w * (v.w - mean) * rstd + sh.w);
  *(ushort4*)(h + e) = *(ushort4*)ob;
}

// --- split-K x4 reduce: out = out + P0+P1+P2+P3 + bias (P bf16) -------------
__global__ __launch_bounds__(256) void reduce4_kernel(const bf16_t* __restrict__ P,
                                                      size_t slice,
                                                      const float* __restrict__ bias,
                                                      float* __restrict__ out,
                                                      int N) {
  const size_t e = ((size_t)blockIdx.x * 256 + threadIdx.x) * 4;
  const ushort* Pu = (const ushort*)P;
  const ushort4 p0 = *(const ushort4*)(Pu + e);
  const ushort4 p1 = *(const ushort4*)(Pu + slice + e);
  const ushort4 p2 = *(const ushort4*)(Pu + 2 * slice + e);
  const ushort4 p3 = *(const ushort4*)(Pu + 3 * slice + e);
  const float4 r = *(const float4*)(out + e);
  const float4 bb = *(const float4*)(bias + (int)(e % N));
  float4 o;
  o.x = r.x + bb.x + bf2f(p0.x) + bf2f(p1.x) + bf2f(p2.x) + bf2f(p3.x);
  o.y = r.y + bb.y + bf2f(p0.y) + bf2f(p1.y) + bf2f(p2.y) + bf2f(p3.y);
  o.z = r.z + bb.z + bf2f(p0.z) + bf2f(p1.z) + bf2f(p2.z) + bf2f(p3.z);
  o.w = r.w + bb.w + bf2f(p0.w) + bf2f(p1.w) + bf2f(p2.w) + bf2f(p3.w);
  *(float4*)(out + e) = o;
}

// ---------------- MFMA flash attention (fixed-max softmax) -------------------
// QKV packed [B*S, 3072]. One block per (b, h, 64-row q-tile); 4 waves;
// wave w owns q-rows w*16..w*16+15. Fixed-max softmax: p = exp(s/8),
// l accumulated on the matrix pipe via all-ones B fragment.
__global__ __launch_bounds__(256) void fattn_kernel(const bf16_t* __restrict__ QKV,
                                                    const int* __restrict__ mask,
                                                    bf16_t* __restrict__ O) {
  const int qt = gridDim.x - 1 - blockIdx.x;  // heavy tiles first
  const int h = blockIdx.y, b = blockIdx.z;
  const int tid = threadIdx.x;
  const int lane = tid & 63, w = tid >> 6;
  const int tx = lane & 15, quad = lane >> 4;
  const int q0 = qt * 64;

  __shared__ ushort Ks[64 * 72];  // K-tile row-major [j][d], pad 72
  __shared__ ushort Vt[64 * 72];  // V-tile transposed [d][j], pad 72
  __shared__ ushort Ps[64 * 72];  // P row-major [q][j], pad 72

  const ushort* qkv = (const ushort*)QKV;
  const size_t rowb = (size_t)b * S_ * 3072;
  const int qoff = h * HD_, koff = D_ + h * HD_, voff = 2 * D_ + h * HD_;

  bf16x8 qf[2];
#pragma unroll
  for (int ks = 0; ks < 2; ks++)
    qf[ks] = *(const bf16x8*)(qkv + rowb +
        (size_t)(q0 + w * 16 + tx) * 3072 + qoff + ks * 32 + quad * 8);

  const short oneb = 0x3F80;  // bf16 1.0
  bf16x8 vones = {oneb, oneb, oneb, oneb, oneb, oneb, oneb, oneb};

  floatx4 ctx[4], lacc;
#pragma unroll
  for (int nt = 0; nt < 4; nt++) {
    ctx[nt].x = 0.f; ctx[nt].y = 0.f; ctx[nt].z = 0.f; ctx[nt].w = 0.f;
  }
  lacc.x = 0.f; lacc.y = 0.f; lacc.z = 0.f; lacc.w = 0.f;

  for (int kt = 0; kt <= qt; kt++) {
    const int k0 = kt * 64;
    __syncthreads();
#pragma unroll
    for (int i = 0; i < 2; i++) {
      const int e = tid + i * 256;
      const int r = e >> 3, ch = (e & 7) * 8;
      *(uint4*)&Ks[r * 72 + ch] =
          *(const uint4*)(qkv + rowb + (size_t)(k0 + r) * 3072 + koff + ch);
    }
#pragma unroll
    for (int i = 0; i < 2; i++) {
      const int r = tid & 63;
      const int c8 = (tid >> 6) * 8 + i * 32;
      uint4 u = *(const uint4*)(qkv + rowb + (size_t)(k0 + r) * 3072 + voff + c8);
      const ushort* sv = (const ushort*)&u;
#pragma unroll
      for (int j = 0; j < 8; j++) Vt[(c8 + j) * 72 + r] = sv[j];
    }
    __syncthreads();

    floatx4 accS[4];
#pragma unroll
    for (int nt = 0; nt < 4; nt++) {
      accS[nt].x = 0.f; accS[nt].y = 0.f; accS[nt].z = 0.f; accS[nt].w = 0.f;
    }
#pragma unroll
    for (int ks = 0; ks < 2; ks++) {
      bf16x8 kf[4];
#pragma unroll
      for (int nt = 0; nt < 4; nt++)
        kf[nt] = *(const bf16x8*)&Ks[(nt * 16 + tx) * 72 + ks * 32 + quad * 8];
#pragma unroll
      for (int nt = 0; nt < 4; nt++)
        accS[nt] = __builtin_amdgcn_mfma_f32_16x16x32_bf16(qf[ks], kf[nt],
                                                           accS[nt], 0, 0, 0);
    }

#pragma unroll
    for (int nt = 0; nt < 4; nt++) {
      const int jc = k0 + nt * 16 + tx;
      const bool ok = mask[b * S_ + jc] != 0;
#pragma unroll
      for (int r = 0; r < 4; r++) {
        const int qrow = q0 + w * 16 + quad * 4 + r;
        float p = exp2f(accS[nt][r] * 0.1803368801111244f);  // 0.125*log2(e)
        if (jc > qrow || !ok) p = 0.f;
        Ps[(w * 16 + quad * 4 + r) * 72 + nt * 16 + tx] =
            ((__hip_bfloat16_raw)__float2bfloat16(p)).x;
      }
    }

#pragma unroll
    for (int ks = 0; ks < 2; ks++) {
      const bf16x8 pf = *(const bf16x8*)&Ps[(w * 16 + tx) * 72 + ks * 32 + quad * 8];
      bf16x8 vf[4];
#pragma unroll
      for (int nt = 0; nt < 4; nt++)
        vf[nt] = *(const bf16x8*)&Vt[(nt * 16 + tx) * 72 + ks * 32 + quad * 8];
#pragma unroll
      for (int nt = 0; nt < 4; nt++)
        ctx[nt] = __builtin_amdgcn_mfma_f32_16x16x32_bf16(pf, vf[nt],
                                                          ctx[nt], 0, 0, 0);
      lacc = __builtin_amdgcn_mfma_f32_16x16x32_bf16(pf, vones, lacc, 0, 0, 0);
    }
  }

  const size_t obase = (size_t)b * S_ * D_ + (size_t)h * HD_;
  float rinv[4];
#pragma unroll
  for (int r = 0; r < 4; r++) rinv[r] = 1.0f / lacc[r];
#pragma unroll
  for (int nt = 0; nt < 4; nt++)
#pragma unroll
    for (int r = 0; r < 4; r++) {
      const int q = q0 + w * 16 + quad * 4 + r;
      O[obase + (size_t)q * D_ + nt * 16 + tx] =
          __float2bfloat16(ctx[nt][r] * rinv[r]);
    }
}

extern "C" void kernel_launch(void* const* d_in, const int* in_sizes, int n_in,
                              void* d_out, int out_size, void* d_ws, size_t ws_size,
                              hipStream_t stream) {
  const float* x = (const float*)d_in[0];
  const int* mask = (const int*)d_in[1];
  const float* wq = (const float*)d_in[2];
  const float* wk = (const float*)d_in[3];
  const float* wv = (const float*)d_in[4];
  const float* wo = (const float*)d_in[5];
  const float* bo = (const float*)d_in[6];
  const float* ln1s = (const float*)d_in[7];
  const float* ln1b = (const float*)d_in[8];
  const float* ln2s = (const float*)d_in[9];
  const float* ln2b = (const float*)d_in[10];
  const float* w1 = (const float*)d_in[11];
  const float* b1 = (const float*)d_in[12];
  const float* w2 = (const float*)d_in[13];
  const float* b2 = (const float*)d_in[14];
  float* out = (float*)d_out;

  const int M = B_ * S_;  // 4096
  char* ws = (char*)d_ws;
  const size_t MB = (size_t)1 << 20;
  bf16_t* qkv = (bf16_t*)(ws);                 // [0,24M)
  bf16_t* ffn1 = (bf16_t*)(ws);                // [0,32M)
  bf16_t* ctx = (bf16_t*)(ws + 32 * MB);       // 8 MB
  bf16_t* h = (bf16_t*)(ws + 40 * MB);         // 8 MB
  bf16_t* wqkv_t = (bf16_t*)(ws + 48 * MB);    // [3072,1024] = 6 MB
  bf16_t* wo_t = (bf16_t*)(ws + 54 * MB);      // [1024,1024] = 2 MB
  bf16_t* w1_t = (bf16_t*)(ws + 56 * MB);      // [4096,1024] = 8 MB
  bf16_t* w2_t = (bf16_t*)(ws + 64 * MB);      // [1024,4096] = 8 MB
  // bf16 split-K partials (sequential reuse of dead regions):
  bf16_t* Pa = (bf16_t*)(ws);                  // step 4: qkv dead, 2x8MB in [0,16M)
  bf16_t* Pf = (bf16_t*)(ws + 32 * MB);        // step 7: ctx/h/w*_t dead, 4x8MB in [32,64M)
  const size_t slice = (size_t)M * D_;         // elements per partial

  // 0. convert + transpose weights to bf16 [N,K]
  convt_kernel<<<dim3(32, 32), 256, 0, stream>>>(wq, wqkv_t, D_, D_);
  convt_kernel<<<dim3(32, 32), 256, 0, stream>>>(wk, wqkv_t + (size_t)D_ * D_, D_, D_);
  convt_kernel<<<dim3(32, 32), 256, 0, stream>>>(wv, wqkv_t + (size_t)2 * D_ * D_, D_, D_);
  convt_kernel<<<dim3(32, 32), 256, 0, stream>>>(wo, wo_t, D_, D_);
  convt_kernel<<<dim3(128, 32), 256, 0, stream>>>(w1, w1_t, D_, 4 * D_);
  convt_kernel<<<dim3(32, 128), 256, 0, stream>>>(w2, w2_t, 4 * D_, D_);

  // 1. h = LN1(x) -> bf16
  ln_kernel<<<dim3(M), 256, 0, stream>>>(x, ln1s, ln1b, h);

  // 2. qkv = h @ [wq|wk|wv]  (M x 3072, bf16 out)
  mgemm_kernel<<<dim3(3 * D_ / 128, M / 128), 256, 0, stream>>>(
      h, wqkv_t, nullptr, nullptr, qkv, M, 3 * D_, D_, D_, 0);

  // 3. ctx = softmax(causal(q k^T)/8) v -> bf16 (MFMA flash, fixed-max)
  fattn_kernel<<<dim3(S_ / 64, H_, B_), 256, 0, stream>>>(qkv, mask, ctx);

  // 4. attn-out split-K x2 -> bf16 partials
  mgemm_kernel<<<dim3(D_ / 128, M / 128, 2), 256, 0, stream>>>(
      ctx, wo_t, nullptr, nullptr, Pa, M, D_, D_, D_ / 2, 4);

  // 5. out = x + Pa0 + Pa1 + bo ; h = LN2(out)   (fused)
  reduce2_ln_kernel<<<dim3(M), 256, 0, stream>>>(Pa, slice, x, bo, ln2s, ln2b,
                                                 out, h);

  // 6. ffn1 = gelu(h @ w1 + b1) -> bf16  (M x 4096)
  mgemm_kernel<<<dim3(4 * D_ / 128, M / 128), 256, 0, stream>>>(
      h, w1_t, b1, nullptr, ffn1, M, 4 * D_, D_, D_, 1);

  // 7. ffn2 split-K x4 -> bf16 partials (1024 blocks = 4/CU)
  mgemm_kernel<<<dim3(D_ / 128, M / 128, 4), 256, 0, stream>>>(
      ffn1, w2_t, nullptr, nullptr, Pf, M, D_, 4 * D_, D_, 4);

  // 8. out = out + sum(Pf) + b2
  reduce4_kernel<<<dim3((size_t)M * D_ / 1024), 256, 0, stream>>>(
      Pf, slice, b2, out, D_);
}

// Round 8
// 383.146 us; speedup vs baseline: 1.1270x; 1.1270x over previous
//
#include <hip/hip_runtime.h>
#include <hip/hip_bf16.h>
#include <math.h>

#define B_ 4
#define S_ 1024
#define D_ 1024
#define H_ 16
#define HD_ 64

typedef __hip_bfloat16 bf16_t;
typedef __attribute__((ext_vector_type(8))) short bf16x8;
typedef __attribute__((ext_vector_type(4))) float floatx4;

__device__ __forceinline__ float bf2f(ushort u) {
  return __uint_as_float((unsigned)u << 16);
}

// ---- prep: one launch = LN1 (4096 row-blocks) + all 6 weight transposes ----
// blocks [0,4096): h = LN1(x) rows
// blocks [4096,8192): wq/wk/wv/wo 32x32 transpose tiles (1024 each)
// blocks [8192,12288): w1 tiles   |  [12288,16384): w2 tiles
__global__ __launch_bounds__(256) void prep_kernel(
    const float* __restrict__ x, const float* __restrict__ ln1s,
    const float* __restrict__ ln1b, bf16_t* __restrict__ h,
    const float* __restrict__ wq, const float* __restrict__ wk,
    const float* __restrict__ wv, const float* __restrict__ wo,
    const float* __restrict__ w1, const float* __restrict__ w2,
    bf16_t* __restrict__ wqkv_t, bf16_t* __restrict__ wo_t,
    bf16_t* __restrict__ w1_t, bf16_t* __restrict__ w2_t) {
  const int id = blockIdx.x;
  if (id < 4096) {  // ---- LayerNorm row ----
    const int row = id;
    float4 v = ((const float4*)(x + (size_t)row * D_))[threadIdx.x];
    float s = v.x + v.y + v.z + v.w;
    float ss = v.x * v.x + v.y * v.y + v.z * v.z + v.w * v.w;
#pragma unroll
    for (int off = 32; off > 0; off >>= 1) {
      s += __shfl_xor(s, off);
      ss += __shfl_xor(ss, off);
    }
    __shared__ float ls[4], lss[4], stats[2];
    const int wave = threadIdx.x >> 6, lane = threadIdx.x & 63;
    if (lane == 0) { ls[wave] = s; lss[wave] = ss; }
    __syncthreads();
    if (threadIdx.x == 0) {
      float t = ls[0] + ls[1] + ls[2] + ls[3];
      float tt = lss[0] + lss[1] + lss[2] + lss[3];
      float mean = t * (1.0f / D_);
      stats[0] = mean;
      stats[1] = rsqrtf(tt * (1.0f / D_) - mean * mean + 1e-5f);
    }
    __syncthreads();
    const float mean = stats[0], rstd = stats[1];
    float4 sc = ((const float4*)ln1s)[threadIdx.x];
    float4 sh = ((const float4*)ln1b)[threadIdx.x];
    bf16_t ob[4];
    ob[0] = __float2bfloat16(sc.x * (v.x - mean) * rstd + sh.x);
    ob[1] = __float2bfloat16(sc.y * (v.y - mean) * rstd + sh.y);
    ob[2] = __float2bfloat16(sc.z * (v.z - mean) * rstd + sh.z);
    ob[3] = __float2bfloat16(sc.w * (v.w - mean) * rstd + sh.w);
    *(ushort4*)(h + (size_t)row * D_ + threadIdx.x * 4) = *(ushort4*)ob;
    return;
  }
  // ---- 32x32 transpose tile: W fp32 [K,N] -> Wt bf16 [N,K] ----
  const float* W;
  bf16_t* Wt;
  int K, N, n0, k0;
  if (id < 8192) {
    const int t = id - 4096, which = t >> 10, tile = t & 1023;
    n0 = (tile & 31) * 32;
    k0 = (tile >> 5) * 32;
    K = 1024; N = 1024;
    W = which == 0 ? wq : which == 1 ? wk : which == 2 ? wv : wo;
    Wt = which < 3 ? wqkv_t + (size_t)which * 1024 * 1024 : wo_t;
  } else if (id < 12288) {
    const int tile = id - 8192;
    n0 = (tile & 127) * 32;
    k0 = (tile >> 7) * 32;
    K = 1024; N = 4096;
    W = w1; Wt = w1_t;
  } else {
    const int tile = id - 12288;
    n0 = (tile & 31) * 32;
    k0 = (tile >> 5) * 32;
    K = 4096; N = 1024;
    W = w2; Wt = w2_t;
  }
  __shared__ float t[32][33];
  const int lx = threadIdx.x & 31, ly = threadIdx.x >> 5;  // 32 x 8
#pragma unroll
  for (int r = ly; r < 32; r += 8) t[r][lx] = W[(size_t)(k0 + r) * N + n0 + lx];
  __syncthreads();
#pragma unroll
  for (int r = ly; r < 32; r += 8)
    Wt[(size_t)(n0 + r) * K + k0 + lx] = __float2bfloat16(t[lx][r]);
}

// ------------- bf16 MFMA GEMM: 128x128 tile, BK=64 (half the barriers) ------
// A [M,K] bf16 row-major, Bt [N,K] bf16 row-major. 256 threads = 4 waves 2x2,
// each wave 64x64 via 4x4 MFMA 16x16x32, 2 K-halves per LDS tile.
// LDS layout: row-major [128][64] per matrix, 16B chunks XOR-swizzled within
// each 128B row by (row&7): staging lane fetches global chunk (px ^ ro8),
// fragment reads chunk ((quad+4ks) ^ (fr&7)). Coalescing preserved (permute
// within 128B segment), ds_read_b128 banking 2-way (free).
// mode 0: C bf16 | 1: bias+gelu -> C bf16 | 4: bf16 partial + z*M*N (split-K)
__global__ __launch_bounds__(256) void mgemm_kernel(const bf16_t* __restrict__ A,
                                                    const bf16_t* __restrict__ Bt,
                                                    const float* __restrict__ bias,
                                                    void* __restrict__ C,
                                                    int M, int N, int K, int Kc,
                                                    int mode) {
  __shared__ bf16_t As[128 * 64];
  __shared__ bf16_t Bs[128 * 64];
  const int tid = threadIdx.x;
  const int lane = tid & 63, w = tid >> 6;
  const int m0 = blockIdx.y * 128, n0 = blockIdx.x * 128;
  const int kz0 = blockIdx.z * Kc;
  const int wm = (w >> 1) * 64, wn = (w & 1) * 64;

  floatx4 zero = {0.f, 0.f, 0.f, 0.f};
  floatx4 acc[4][4];
#pragma unroll
  for (int i = 0; i < 4; i++)
#pragma unroll
    for (int j = 0; j < 4; j++) acc[i][j] = zero;

  // staging: chunk c (1KB = 8 rows x 128B) handled by wave c&3, c = w+4t.
  const int ro8 = lane >> 3;                 // row within chunk
  const int g8 = ((lane & 7) ^ ro8) * 8;     // swizzled source col (elements)
  const bf16_t* ga[4];
  const bf16_t* gb[4];
  bf16_t* la[4];
  bf16_t* lb[4];
#pragma unroll
  for (int t = 0; t < 4; t++) {
    const int c = w + 4 * t;
    ga[t] = A + (size_t)(m0 + c * 8 + ro8) * K + g8;
    gb[t] = Bt + (size_t)(n0 + c * 8 + ro8) * K + g8;
    la[t] = &As[c * 512];
    lb[t] = &Bs[c * 512];
  }

  const int fr = lane & 15, quad = lane >> 4;

  for (int k0 = kz0; k0 < kz0 + Kc; k0 += 64) {
    __syncthreads();
#pragma unroll
    for (int t = 0; t < 4; t++) {
      __builtin_amdgcn_global_load_lds(
          (const __attribute__((address_space(1))) void*)(ga[t] + k0),
          (__attribute__((address_space(3))) void*)la[t], 16, 0, 0);
      __builtin_amdgcn_global_load_lds(
          (const __attribute__((address_space(1))) void*)(gb[t] + k0),
          (__attribute__((address_space(3))) void*)lb[t], 16, 0, 0);
    }
    __syncthreads();

#pragma unroll
    for (int ks = 0; ks < 2; ks++) {
      const int sq = ((quad + 4 * ks) ^ (fr & 7)) * 8;
      bf16x8 af[4], bfr[4];
#pragma unroll
      for (int i = 0; i < 4; i++) {
        af[i] = *(const bf16x8*)&As[(wm + i * 16 + fr) * 64 + sq];
        bfr[i] = *(const bf16x8*)&Bs[(wn + i * 16 + fr) * 64 + sq];
      }
#pragma unroll
      for (int i = 0; i < 4; i++)
#pragma unroll
        for (int j = 0; j < 4; j++)
          acc[i][j] = __builtin_amdgcn_mfma_f32_16x16x32_bf16(af[i], bfr[j],
                                                              acc[i][j], 0, 0, 0);
    }
  }

  // epilogue: C/D layout col=lane&15, row=quad*4+reg
  bf16_t* Pz = (mode == 4)
                   ? ((bf16_t*)C + (size_t)blockIdx.z * M * N)
                   : nullptr;
#pragma unroll
  for (int j = 0; j < 4; j++) {
    const int col = n0 + wn + j * 16 + fr;
    const float bj = bias ? bias[col] : 0.f;
#pragma unroll
    for (int i = 0; i < 4; i++) {
      const int rbase = m0 + wm + i * 16 + quad * 4;
#pragma unroll
      for (int r = 0; r < 4; r++) {
        const int row = rbase + r;
        float c = acc[i][j][r] + bj;
        if (mode == 1) {  // gelu(tanh) via fast sigmoid
          const float xg = c;
          const float t = 0.7978845608028654f * (xg + 0.044715f * xg * xg * xg);
          const float th = 2.0f / (1.0f + __expf(-2.0f * t)) - 1.0f;
          c = 0.5f * xg * (1.0f + th);
        }
        if (mode == 4) {
          Pz[(size_t)row * N + col] = __float2bfloat16(c);
        } else {
          ((bf16_t*)C)[(size_t)row * N + col] = __float2bfloat16(c);
        }
      }
    }
  }
}

// --- fused: out = x + P0 + P1 + bias ; h = LN2(out). One block per row. -----
__global__ __launch_bounds__(256) void reduce2_ln_kernel(
    const bf16_t* __restrict__ P, size_t slice, const float* __restrict__ x,
    const float* __restrict__ bias, const float* __restrict__ scale,
    const float* __restrict__ shift, float* __restrict__ out,
    bf16_t* __restrict__ h) {
  const int row = blockIdx.x;
  const size_t e = (size_t)row * D_ + threadIdx.x * 4;
  const float4 xv = *(const float4*)(x + e);
  const ushort4 p0 = *(const ushort4*)((const ushort*)P + e);
  const ushort4 p1 = *(const ushort4*)((const ushort*)P + slice + e);
  const float4 bb = *(const float4*)(bias + threadIdx.x * 4);
  float4 v;
  v.x = xv.x + bf2f(p0.x) + bf2f(p1.x) + bb.x;
  v.y = xv.y + bf2f(p0.y) + bf2f(p1.y) + bb.y;
  v.z = xv.z + bf2f(p0.z) + bf2f(p1.z) + bb.z;
  v.w = xv.w + bf2f(p0.w) + bf2f(p1.w) + bb.w;
  *(float4*)(out + e) = v;

  float s = v.x + v.y + v.z + v.w;
  float ss = v.x * v.x + v.y * v.y + v.z * v.z + v.w * v.w;
#pragma unroll
  for (int off = 32; off > 0; off >>= 1) {
    s += __shfl_xor(s, off);
    ss += __shfl_xor(ss, off);
  }
  __shared__ float ls[4], lss[4], stats[2];
  const int wave = threadIdx.x >> 6, lane = threadIdx.x & 63;
  if (lane == 0) { ls[wave] = s; lss[wave] = ss; }
  __syncthreads();
  if (threadIdx.x == 0) {
    float t = ls[0] + ls[1] + ls[2] + ls[3];
    float tt = lss[0] + lss[1] + lss[2] + lss[3];
    float mean = t * (1.0f / D_);
    stats[0] = mean;
    stats[1] = rsqrtf(tt * (1.0f / D_) - mean * mean + 1e-5f);
  }
  __syncthreads();
  const float mean = stats[0], rstd = stats[1];
  const float4 sc = *(const float4*)(scale + threadIdx.x * 4);
  const float4 sh = *(const float4*)(shift + threadIdx.x * 4);
  bf16_t ob[4];
  ob[0] = __float2bfloat16(sc.x * (v.x - mean) * rstd + sh.x);
  ob[1] = __float2bfloat16(sc.y * (v.y - mean) * rstd + sh.y);
  ob[2] = __float2bfloat16(sc.z * (v.z - mean) * rstd + sh.z);
  ob[3] = __float2bfloat16(sc.w * (v.w - mean) * rstd + sh.w);
  *(ushort4*)(h + e) = *(ushort4*)ob;
}

// --- split-K x4 reduce: out = out + P0+P1+P2+P3 + bias (P bf16) -------------
__global__ __launch_bounds__(256) void reduce4_kernel(const bf16_t* __restrict__ P,
                                                      size_t slice,
                                                      const float* __restrict__ bias,
                                                      float* __restrict__ out,
                                                      int N) {
  const size_t e = ((size_t)blockIdx.x * 256 + threadIdx.x) * 4;
  const ushort* Pu = (const ushort*)P;
  const ushort4 p0 = *(const ushort4*)(Pu + e);
  const ushort4 p1 = *(const ushort4*)(Pu + slice + e);
  const ushort4 p2 = *(const ushort4*)(Pu + 2 * slice + e);
  const ushort4 p3 = *(const ushort4*)(Pu + 3 * slice + e);
  const float4 r = *(const float4*)(out + e);
  const float4 bb = *(const float4*)(bias + (int)(e % N));
  float4 o;
  o.x = r.x + bb.x + bf2f(p0.x) + bf2f(p1.x) + bf2f(p2.x) + bf2f(p3.x);
  o.y = r.y + bb.y + bf2f(p0.y) + bf2f(p1.y) + bf2f(p2.y) + bf2f(p3.y);
  o.z = r.z + bb.z + bf2f(p0.z) + bf2f(p1.z) + bf2f(p2.z) + bf2f(p3.z);
  o.w = r.w + bb.w + bf2f(p0.w) + bf2f(p1.w) + bf2f(p2.w) + bf2f(p3.w);
  *(float4*)(out + e) = o;
}

// ---------------- MFMA flash attention (fixed-max softmax) -------------------
__global__ __launch_bounds__(256) void fattn_kernel(const bf16_t* __restrict__ QKV,
                                                    const int* __restrict__ mask,
                                                    bf16_t* __restrict__ O) {
  const int qt = gridDim.x - 1 - blockIdx.x;  // heavy tiles first
  const int h = blockIdx.y, b = blockIdx.z;
  const int tid = threadIdx.x;
  const int lane = tid & 63, w = tid >> 6;
  const int tx = lane & 15, quad = lane >> 4;
  const int q0 = qt * 64;

  __shared__ ushort Ks[64 * 72];  // K-tile row-major [j][d], pad 72
  __shared__ ushort Vt[64 * 72];  // V-tile transposed [d][j], pad 72
  __shared__ ushort Ps[64 * 72];  // P row-major [q][j], pad 72

  const ushort* qkv = (const ushort*)QKV;
  const size_t rowb = (size_t)b * S_ * 3072;
  const int koff = D_ + h * HD_, voff = 2 * D_ + h * HD_;

  bf16x8 qf[2];
#pragma unroll
  for (int ks = 0; ks < 2; ks++)
    qf[ks] = *(const bf16x8*)(qkv + rowb +
        (size_t)(q0 + w * 16 + tx) * 3072 + h * HD_ + ks * 32 + quad * 8);

  const short oneb = 0x3F80;  // bf16 1.0
  bf16x8 vones = {oneb, oneb, oneb, oneb, oneb, oneb, oneb, oneb};

  floatx4 ctx[4], lacc;
#pragma unroll
  for (int nt = 0; nt < 4; nt++) {
    ctx[nt].x = 0.f; ctx[nt].y = 0.f; ctx[nt].z = 0.f; ctx[nt].w = 0.f;
  }
  lacc.x = 0.f; lacc.y = 0.f; lacc.z = 0.f; lacc.w = 0.f;

  for (int kt = 0; kt <= qt; kt++) {
    const int k0 = kt * 64;
    __syncthreads();
#pragma unroll
    for (int i = 0; i < 2; i++) {
      const int e = tid + i * 256;
      const int r = e >> 3, ch = (e & 7) * 8;
      *(uint4*)&Ks[r * 72 + ch] =
          *(const uint4*)(qkv + rowb + (size_t)(k0 + r) * 3072 + koff + ch);
    }
#pragma unroll
    for (int i = 0; i < 2; i++) {
      const int r = tid & 63;
      const int c8 = (tid >> 6) * 8 + i * 32;
      uint4 u = *(const uint4*)(qkv + rowb + (size_t)(k0 + r) * 3072 + voff + c8);
      const ushort* sv = (const ushort*)&u;
#pragma unroll
      for (int j = 0; j < 8; j++) Vt[(c8 + j) * 72 + r] = sv[j];
    }
    __syncthreads();

    floatx4 accS[4];
#pragma unroll
    for (int nt = 0; nt < 4; nt++) {
      accS[nt].x = 0.f; accS[nt].y = 0.f; accS[nt].z = 0.f; accS[nt].w = 0.f;
    }
#pragma unroll
    for (int ks = 0; ks < 2; ks++) {
      bf16x8 kf[4];
#pragma unroll
      for (int nt = 0; nt < 4; nt++)
        kf[nt] = *(const bf16x8*)&Ks[(nt * 16 + tx) * 72 + ks * 32 + quad * 8];
#pragma unroll
      for (int nt = 0; nt < 4; nt++)
        accS[nt] = __builtin_amdgcn_mfma_f32_16x16x32_bf16(qf[ks], kf[nt],
                                                           accS[nt], 0, 0, 0);
    }

#pragma unroll
    for (int nt = 0; nt < 4; nt++) {
      const int jc = k0 + nt * 16 + tx;
      const bool ok = mask[b * S_ + jc] != 0;
#pragma unroll
      for (int r = 0; r < 4; r++) {
        const int qrow = q0 + w * 16 + quad * 4 + r;
        float p = exp2f(accS[nt][r] * 0.1803368801111244f);  // 0.125*log2(e)
        if (jc > qrow || !ok) p = 0.f;
        Ps[(w * 16 + quad * 4 + r) * 72 + nt * 16 + tx] =
            ((__hip_bfloat16_raw)__float2bfloat16(p)).x;
      }
    }

#pragma unroll
    for (int ks = 0; ks < 2; ks++) {
      const bf16x8 pf = *(const bf16x8*)&Ps[(w * 16 + tx) * 72 + ks * 32 + quad * 8];
      bf16x8 vf[4];
#pragma unroll
      for (int nt = 0; nt < 4; nt++)
        vf[nt] = *(const bf16x8*)&Vt[(nt * 16 + tx) * 72 + ks * 32 + quad * 8];
#pragma unroll
      for (int nt = 0; nt < 4; nt++)
        ctx[nt] = __builtin_amdgcn_mfma_f32_16x16x32_bf16(pf, vf[nt],
                                                          ctx[nt], 0, 0, 0);
      lacc = __builtin_amdgcn_mfma_f32_16x16x32_bf16(pf, vones, lacc, 0, 0, 0);
    }
  }

  const size_t obase = (size_t)b * S_ * D_ + (size_t)h * HD_;
  float rinv[4];
#pragma unroll
  for (int r = 0; r < 4; r++) rinv[r] = 1.0f / lacc[r];
#pragma unroll
  for (int nt = 0; nt < 4; nt++)
#pragma unroll
    for (int r = 0; r < 4; r++) {
      const int q = q0 + w * 16 + quad * 4 + r;
      O[obase + (size_t)q * D_ + nt * 16 + tx] =
          __float2bfloat16(ctx[nt][r] * rinv[r]);
    }
}

extern "C" void kernel_launch(void* const* d_in, const int* in_sizes, int n_in,
                              void* d_out, int out_size, void* d_ws, size_t ws_size,
                              hipStream_t stream) {
  const float* x = (const float*)d_in[0];
  const int* mask = (const int*)d_in[1];
  const float* wq = (const float*)d_in[2];
  const float* wk = (const float*)d_in[3];
  const float* wv = (const float*)d_in[4];
  const float* wo = (const float*)d_in[5];
  const float* bo = (const float*)d_in[6];
  const float* ln2s = (const float*)d_in[9];
  const float* ln2b = (const float*)d_in[10];
  const float* w1 = (const float*)d_in[11];
  const float* b1 = (const float*)d_in[12];
  const float* w2 = (const float*)d_in[13];
  const float* b2 = (const float*)d_in[14];
  float* out = (float*)d_out;

  const int M = B_ * S_;  // 4096
  char* ws = (char*)d_ws;
  const size_t MB = (size_t)1 << 20;
  bf16_t* qkv = (bf16_t*)(ws);                 // [0,24M)
  bf16_t* ffn1 = (bf16_t*)(ws);                // [0,32M)
  bf16_t* ctx = (bf16_t*)(ws + 32 * MB);       // 8 MB
  bf16_t* h = (bf16_t*)(ws + 40 * MB);         // 8 MB
  bf16_t* wqkv_t = (bf16_t*)(ws + 48 * MB);    // [3072,1024] = 6 MB
  bf16_t* wo_t = (bf16_t*)(ws + 54 * MB);      // [1024,1024] = 2 MB
  bf16_t* w1_t = (bf16_t*)(ws + 56 * MB);      // [4096,1024] = 8 MB
  bf16_t* w2_t = (bf16_t*)(ws + 64 * MB);      // [1024,4096] = 8 MB
  bf16_t* Pa = (bf16_t*)(ws);                  // step 4: qkv dead, 2x8MB
  bf16_t* Pf = (bf16_t*)(ws + 32 * MB);        // step 7: ctx/h/w*_t dead, 4x8MB
  const size_t slice = (size_t)M * D_;

  // 1. prep: h = LN1(x) + all weight transposes (one launch)
  prep_kernel<<<dim3(16384), 256, 0, stream>>>(x, (const float*)d_in[7],
                                               (const float*)d_in[8], h, wq, wk,
                                               wv, wo, w1, w2, wqkv_t, wo_t,
                                               w1_t, w2_t);

  // 2. qkv = h @ [wq|wk|wv]  (M x 3072, bf16 out)
  mgemm_kernel<<<dim3(3 * D_ / 128, M / 128), 256, 0, stream>>>(
      h, wqkv_t, nullptr, qkv, M, 3 * D_, D_, D_, 0);

  // 3. ctx = softmax(causal(q k^T)/8) v -> bf16 (MFMA flash, fixed-max)
  fattn_kernel<<<dim3(S_ / 64, H_, B_), 256, 0, stream>>>(qkv, mask, ctx);

  // 4. attn-out split-K x2 -> bf16 partials
  mgemm_kernel<<<dim3(D_ / 128, M / 128, 2), 256, 0, stream>>>(
      ctx, wo_t, nullptr, Pa, M, D_, D_, D_ / 2, 4);

  // 5. out = x + Pa0 + Pa1 + bo ; h = LN2(out)   (fused)
  reduce2_ln_kernel<<<dim3(M), 256, 0, stream>>>(Pa, slice, x, bo, ln2s, ln2b,
                                                 out, h);

  // 6. ffn1 = gelu(h @ w1 + b1) -> bf16  (M x 4096)
  mgemm_kernel<<<dim3(4 * D_ / 128, M / 128), 256, 0, stream>>>(
      h, w1_t, b1, ffn1, M, 4 * D_, D_, D_, 1);

  // 7. ffn2 split-K x4 -> bf16 partials
  mgemm_kernel<<<dim3(D_ / 128, M / 128, 4), 256, 0, stream>>>(
      ffn1, w2_t, nullptr, Pf, M, D_, 4 * D_, D_, 4);

  // 8. out = out + sum(Pf) + b2
  reduce4_kernel<<<dim3((size_t)M * D_ / 1024), 256, 0, stream>>>(
      Pf, slice, b2, out, D_);
}

// Round 9
// 375.852 us; speedup vs baseline: 1.1488x; 1.0194x over previous
//
#include <hip/hip_runtime.h>
#include <hip/hip_bf16.h>
#include <math.h>

#define B_ 4
#define S_ 1024
#define D_ 1024
#define H_ 16
#define HD_ 64

typedef __hip_bfloat16 bf16_t;
typedef __attribute__((ext_vector_type(8))) short bf16x8;
typedef __attribute__((ext_vector_type(4))) float floatx4;

__device__ __forceinline__ float bf2f(ushort u) {
  return __uint_as_float((unsigned)u << 16);
}

// ---- prep: one launch = LN1 (4096 row-blocks) + all 6 weight transposes ----
__global__ __launch_bounds__(256) void prep_kernel(
    const float* __restrict__ x, const float* __restrict__ ln1s,
    const float* __restrict__ ln1b, bf16_t* __restrict__ h,
    const float* __restrict__ wq, const float* __restrict__ wk,
    const float* __restrict__ wv, const float* __restrict__ wo,
    const float* __restrict__ w1, const float* __restrict__ w2,
    bf16_t* __restrict__ wqkv_t, bf16_t* __restrict__ wo_t,
    bf16_t* __restrict__ w1_t, bf16_t* __restrict__ w2_t) {
  const int id = blockIdx.x;
  if (id < 4096) {  // ---- LayerNorm row ----
    const int row = id;
    float4 v = ((const float4*)(x + (size_t)row * D_))[threadIdx.x];
    float s = v.x + v.y + v.z + v.w;
    float ss = v.x * v.x + v.y * v.y + v.z * v.z + v.w * v.w;
#pragma unroll
    for (int off = 32; off > 0; off >>= 1) {
      s += __shfl_xor(s, off);
      ss += __shfl_xor(ss, off);
    }
    __shared__ float ls[4], lss[4], stats[2];
    const int wave = threadIdx.x >> 6, lane = threadIdx.x & 63;
    if (lane == 0) { ls[wave] = s; lss[wave] = ss; }
    __syncthreads();
    if (threadIdx.x == 0) {
      float t = ls[0] + ls[1] + ls[2] + ls[3];
      float tt = lss[0] + lss[1] + lss[2] + lss[3];
      float mean = t * (1.0f / D_);
      stats[0] = mean;
      stats[1] = rsqrtf(tt * (1.0f / D_) - mean * mean + 1e-5f);
    }
    __syncthreads();
    const float mean = stats[0], rstd = stats[1];
    float4 sc = ((const float4*)ln1s)[threadIdx.x];
    float4 sh = ((const float4*)ln1b)[threadIdx.x];
    bf16_t ob[4];
    ob[0] = __float2bfloat16(sc.x * (v.x - mean) * rstd + sh.x);
    ob[1] = __float2bfloat16(sc.y * (v.y - mean) * rstd + sh.y);
    ob[2] = __float2bfloat16(sc.z * (v.z - mean) * rstd + sh.z);
    ob[3] = __float2bfloat16(sc.w * (v.w - mean) * rstd + sh.w);
    *(ushort4*)(h + (size_t)row * D_ + threadIdx.x * 4) = *(ushort4*)ob;
    return;
  }
  const float* W;
  bf16_t* Wt;
  int K, N, n0, k0;
  if (id < 8192) {
    const int t = id - 4096, which = t >> 10, tile = t & 1023;
    n0 = (tile & 31) * 32;
    k0 = (tile >> 5) * 32;
    K = 1024; N = 1024;
    W = which == 0 ? wq : which == 1 ? wk : which == 2 ? wv : wo;
    Wt = which < 3 ? wqkv_t + (size_t)which * 1024 * 1024 : wo_t;
  } else if (id < 12288) {
    const int tile = id - 8192;
    n0 = (tile & 127) * 32;
    k0 = (tile >> 7) * 32;
    K = 1024; N = 4096;
    W = w1; Wt = w1_t;
  } else {
    const int tile = id - 12288;
    n0 = (tile & 31) * 32;
    k0 = (tile >> 5) * 32;
    K = 4096; N = 1024;
    W = w2; Wt = w2_t;
  }
  __shared__ float t[32][33];
  const int lx = threadIdx.x & 31, ly = threadIdx.x >> 5;  // 32 x 8
#pragma unroll
  for (int r = ly; r < 32; r += 8) t[r][lx] = W[(size_t)(k0 + r) * N + n0 + lx];
  __syncthreads();
#pragma unroll
  for (int r = ly; r < 32; r += 8)
    Wt[(size_t)(n0 + r) * K + k0 + lx] = __float2bfloat16(t[lx][r]);
}

// ------------- bf16 MFMA GEMM: 128x128 tile, BK=64, XCD-clustered ------------
// 1D grid; flat block id decoded so XCD (= flat%8 heuristic) j gets the
// (m-band, n-band) cluster (j%PM, j/PM): per-XCD L2 sees A/PM + B/PN instead
// of the whole A. m varies fastest within an XCD (temporal B-stripe reuse).
// Mt = m-tiles per band, Nt = n-tiles per band.
// mode 0: C bf16 | 1: bias+gelu -> C bf16 | 4: bf16 partial + z*M*N (split-K)
__global__ __launch_bounds__(256) void mgemm_kernel(const bf16_t* __restrict__ A,
                                                    const bf16_t* __restrict__ Bt,
                                                    const float* __restrict__ bias,
                                                    void* __restrict__ C,
                                                    int M, int N, int K, int Kc,
                                                    int Mt, int Nt, int PM,
                                                    int mode) {
  __shared__ bf16_t As[128 * 64];
  __shared__ bf16_t Bs[128 * 64];
  const int tid = threadIdx.x;
  const int lane = tid & 63, w = tid >> 6;

  // --- XCD-cluster decode ---
  const int flat = blockIdx.x;
  const int xcd = flat & 7;
  int t0 = flat >> 3;
  const int mb = xcd % PM, nb = xcd / PM;
  const int mt = mb * Mt + (t0 % Mt);
  t0 /= Mt;
  const int nt = nb * Nt + (t0 % Nt);
  const int z = t0 / Nt;
  const int m0 = mt * 128, n0 = nt * 128;
  const int kz0 = z * Kc;
  const int wm = (w >> 1) * 64, wn = (w & 1) * 64;

  floatx4 zero = {0.f, 0.f, 0.f, 0.f};
  floatx4 acc[4][4];
#pragma unroll
  for (int i = 0; i < 4; i++)
#pragma unroll
    for (int j = 0; j < 4; j++) acc[i][j] = zero;

  // staging: chunk c (1KB = 8 rows x 128B) handled by wave c&3, c = w+4t.
  const int ro8 = lane >> 3;                 // row within chunk
  const int g8 = ((lane & 7) ^ ro8) * 8;     // swizzled source col (elements)
  const bf16_t* ga[4];
  const bf16_t* gb[4];
  bf16_t* la[4];
  bf16_t* lb[4];
#pragma unroll
  for (int t = 0; t < 4; t++) {
    const int c = w + 4 * t;
    ga[t] = A + (size_t)(m0 + c * 8 + ro8) * K + g8;
    gb[t] = Bt + (size_t)(n0 + c * 8 + ro8) * K + g8;
    la[t] = &As[c * 512];
    lb[t] = &Bs[c * 512];
  }

  const int fr = lane & 15, quad = lane >> 4;

  for (int k0 = kz0; k0 < kz0 + Kc; k0 += 64) {
    __syncthreads();
#pragma unroll
    for (int t = 0; t < 4; t++) {
      __builtin_amdgcn_global_load_lds(
          (const __attribute__((address_space(1))) void*)(ga[t] + k0),
          (__attribute__((address_space(3))) void*)la[t], 16, 0, 0);
      __builtin_amdgcn_global_load_lds(
          (const __attribute__((address_space(1))) void*)(gb[t] + k0),
          (__attribute__((address_space(3))) void*)lb[t], 16, 0, 0);
    }
    __syncthreads();

#pragma unroll
    for (int ks = 0; ks < 2; ks++) {
      const int sq = ((quad + 4 * ks) ^ (fr & 7)) * 8;
      bf16x8 af[4], bfr[4];
#pragma unroll
      for (int i = 0; i < 4; i++) {
        af[i] = *(const bf16x8*)&As[(wm + i * 16 + fr) * 64 + sq];
        bfr[i] = *(const bf16x8*)&Bs[(wn + i * 16 + fr) * 64 + sq];
      }
#pragma unroll
      for (int i = 0; i < 4; i++)
#pragma unroll
        for (int j = 0; j < 4; j++)
          acc[i][j] = __builtin_amdgcn_mfma_f32_16x16x32_bf16(af[i], bfr[j],
                                                              acc[i][j], 0, 0, 0);
    }
  }

  // epilogue: C/D layout col=lane&15, row=quad*4+reg
  bf16_t* Pz = (mode == 4) ? ((bf16_t*)C + (size_t)z * M * N) : nullptr;
#pragma unroll
  for (int j = 0; j < 4; j++) {
    const int col = n0 + wn + j * 16 + fr;
    const float bj = bias ? bias[col] : 0.f;
#pragma unroll
    for (int i = 0; i < 4; i++) {
      const int rbase = m0 + wm + i * 16 + quad * 4;
#pragma unroll
      for (int r = 0; r < 4; r++) {
        const int row = rbase + r;
        float c = acc[i][j][r] + bj;
        if (mode == 1) {  // gelu(tanh) via fast sigmoid
          const float xg = c;
          const float t = 0.7978845608028654f * (xg + 0.044715f * xg * xg * xg);
          const float th = 2.0f / (1.0f + __expf(-2.0f * t)) - 1.0f;
          c = 0.5f * xg * (1.0f + th);
        }
        if (mode == 4) {
          Pz[(size_t)row * N + col] = __float2bfloat16(c);
        } else {
          ((bf16_t*)C)[(size_t)row * N + col] = __float2bfloat16(c);
        }
      }
    }
  }
}

// --- fused: out = x + P0 + P1 + bias ; h = LN2(out). One block per row. -----
__global__ __launch_bounds__(256) void reduce2_ln_kernel(
    const bf16_t* __restrict__ P, size_t slice, const float* __restrict__ x,
    const float* __restrict__ bias, const float* __restrict__ scale,
    const float* __restrict__ shift, float* __restrict__ out,
    bf16_t* __restrict__ h) {
  const int row = blockIdx.x;
  const size_t e = (size_t)row * D_ + threadIdx.x * 4;
  const float4 xv = *(const float4*)(x + e);
  const ushort4 p0 = *(const ushort4*)((const ushort*)P + e);
  const ushort4 p1 = *(const ushort4*)((const ushort*)P + slice + e);
  const float4 bb = *(const float4*)(bias + threadIdx.x * 4);
  float4 v;
  v.x = xv.x + bf2f(p0.x) + bf2f(p1.x) + bb.x;
  v.y = xv.y + bf2f(p0.y) + bf2f(p1.y) + bb.y;
  v.z = xv.z + bf2f(p0.z) + bf2f(p1.z) + bb.z;
  v.w = xv.w + bf2f(p0.w) + bf2f(p1.w) + bb.w;
  *(float4*)(out + e) = v;

  float s = v.x + v.y + v.z + v.w;
  float ss = v.x * v.x + v.y * v.y + v.z * v.z + v.w * v.w;
#pragma unroll
  for (int off = 32; off > 0; off >>= 1) {
    s += __shfl_xor(s, off);
    ss += __shfl_xor(ss, off);
  }
  __shared__ float ls[4], lss[4], stats[2];
  const int wave = threadIdx.x >> 6, lane = threadIdx.x & 63;
  if (lane == 0) { ls[wave] = s; lss[wave] = ss; }
  __syncthreads();
  if (threadIdx.x == 0) {
    float t = ls[0] + ls[1] + ls[2] + ls[3];
    float tt = lss[0] + lss[1] + lss[2] + lss[3];
    float mean = t * (1.0f / D_);
    stats[0] = mean;
    stats[1] = rsqrtf(tt * (1.0f / D_) - mean * mean + 1e-5f);
  }
  __syncthreads();
  const float mean = stats[0], rstd = stats[1];
  const float4 sc = *(const float4*)(scale + threadIdx.x * 4);
  const float4 sh = *(const float4*)(shift + threadIdx.x * 4);
  bf16_t ob[4];
  ob[0] = __float2bfloat16(sc.x * (v.x - mean) * rstd + sh.x);
  ob[1] = __float2bfloat16(sc.y * (v.y - mean) * rstd + sh.y);
  ob[2] = __float2bfloat16(sc.z * (v.z - mean) * rstd + sh.z);
  ob[3] = __float2bfloat16(sc.w * (v.w - mean) * rstd + sh.w);
  *(ushort4*)(h + e) = *(ushort4*)ob;
}

// --- split-K x4 reduce: out = out + P0+P1+P2+P3 + bias (P bf16) -------------
__global__ __launch_bounds__(256) void reduce4_kernel(const bf16_t* __restrict__ P,
                                                      size_t slice,
                                                      const float* __restrict__ bias,
                                                      float* __restrict__ out,
                                                      int N) {
  const size_t e = ((size_t)blockIdx.x * 256 + threadIdx.x) * 4;
  const ushort* Pu = (const ushort*)P;
  const ushort4 p0 = *(const ushort4*)(Pu + e);
  const ushort4 p1 = *(const ushort4*)(Pu + slice + e);
  const ushort4 p2 = *(const ushort4*)(Pu + 2 * slice + e);
  const ushort4 p3 = *(const ushort4*)(Pu + 3 * slice + e);
  const float4 r = *(const float4*)(out + e);
  const float4 bb = *(const float4*)(bias + (int)(e % N));
  float4 o;
  o.x = r.x + bb.x + bf2f(p0.x) + bf2f(p1.x) + bf2f(p2.x) + bf2f(p3.x);
  o.y = r.y + bb.y + bf2f(p0.y) + bf2f(p1.y) + bf2f(p2.y) + bf2f(p3.y);
  o.z = r.z + bb.z + bf2f(p0.z) + bf2f(p1.z) + bf2f(p2.z) + bf2f(p3.z);
  o.w = r.w + bb.w + bf2f(p0.w) + bf2f(p1.w) + bf2f(p2.w) + bf2f(p3.w);
  *(float4*)(out + e) = o;
}

// ---------------- MFMA flash attention (fixed-max softmax) -------------------
__global__ __launch_bounds__(256) void fattn_kernel(const bf16_t* __restrict__ QKV,
                                                    const int* __restrict__ mask,
                                                    bf16_t* __restrict__ O) {
  const int qt = gridDim.x - 1 - blockIdx.x;  // heavy tiles first
  const int h = blockIdx.y, b = blockIdx.z;
  const int tid = threadIdx.x;
  const int lane = tid & 63, w = tid >> 6;
  const int tx = lane & 15, quad = lane >> 4;
  const int q0 = qt * 64;

  __shared__ ushort Ks[64 * 72];  // K-tile row-major [j][d], pad 72
  __shared__ ushort Vt[64 * 72];  // V-tile transposed [d][j], pad 72
  __shared__ ushort Ps[64 * 72];  // P row-major [q][j], pad 72

  const ushort* qkv = (const ushort*)QKV;
  const size_t rowb = (size_t)b * S_ * 3072;
  const int koff = D_ + h * HD_, voff = 2 * D_ + h * HD_;

  bf16x8 qf[2];
#pragma unroll
  for (int ks = 0; ks < 2; ks++)
    qf[ks] = *(const bf16x8*)(qkv + rowb +
        (size_t)(q0 + w * 16 + tx) * 3072 + h * HD_ + ks * 32 + quad * 8);

  const short oneb = 0x3F80;  // bf16 1.0
  bf16x8 vones = {oneb, oneb, oneb, oneb, oneb, oneb, oneb, oneb};

  floatx4 ctx[4], lacc;
#pragma unroll
  for (int nt = 0; nt < 4; nt++) {
    ctx[nt].x = 0.f; ctx[nt].y = 0.f; ctx[nt].z = 0.f; ctx[nt].w = 0.f;
  }
  lacc.x = 0.f; lacc.y = 0.f; lacc.z = 0.f; lacc.w = 0.f;

  for (int kt = 0; kt <= qt; kt++) {
    const int k0 = kt * 64;
    __syncthreads();
#pragma unroll
    for (int i = 0; i < 2; i++) {
      const int e = tid + i * 256;
      const int r = e >> 3, ch = (e & 7) * 8;
      *(uint4*)&Ks[r * 72 + ch] =
          *(const uint4*)(qkv + rowb + (size_t)(k0 + r) * 3072 + koff + ch);
    }
#pragma unroll
    for (int i = 0; i < 2; i++) {
      const int r = tid & 63;
      const int c8 = (tid >> 6) * 8 + i * 32;
      uint4 u = *(const uint4*)(qkv + rowb + (size_t)(k0 + r) * 3072 + voff + c8);
      const ushort* sv = (const ushort*)&u;
#pragma unroll
      for (int j = 0; j < 8; j++) Vt[(c8 + j) * 72 + r] = sv[j];
    }
    __syncthreads();

    floatx4 accS[4];
#pragma unroll
    for (int nt = 0; nt < 4; nt++) {
      accS[nt].x = 0.f; accS[nt].y = 0.f; accS[nt].z = 0.f; accS[nt].w = 0.f;
    }
#pragma unroll
    for (int ks = 0; ks < 2; ks++) {
      bf16x8 kf[4];
#pragma unroll
      for (int nt = 0; nt < 4; nt++)
        kf[nt] = *(const bf16x8*)&Ks[(nt * 16 + tx) * 72 + ks * 32 + quad * 8];
#pragma unroll
      for (int nt = 0; nt < 4; nt++)
        accS[nt] = __builtin_amdgcn_mfma_f32_16x16x32_bf16(qf[ks], kf[nt],
                                                           accS[nt], 0, 0, 0);
    }

#pragma unroll
    for (int nt = 0; nt < 4; nt++) {
      const int jc = k0 + nt * 16 + tx;
      const bool ok = mask[b * S_ + jc] != 0;
#pragma unroll
      for (int r = 0; r < 4; r++) {
        const int qrow = q0 + w * 16 + quad * 4 + r;
        float p = exp2f(accS[nt][r] * 0.1803368801111244f);  // 0.125*log2(e)
        if (jc > qrow || !ok) p = 0.f;
        Ps[(w * 16 + quad * 4 + r) * 72 + nt * 16 + tx] =
            ((__hip_bfloat16_raw)__float2bfloat16(p)).x;
      }
    }

#pragma unroll
    for (int ks = 0; ks < 2; ks++) {
      const bf16x8 pf = *(const bf16x8*)&Ps[(w * 16 + tx) * 72 + ks * 32 + quad * 8];
      bf16x8 vf[4];
#pragma unroll
      for (int nt = 0; nt < 4; nt++)
        vf[nt] = *(const bf16x8*)&Vt[(nt * 16 + tx) * 72 + ks * 32 + quad * 8];
#pragma unroll
      for (int nt = 0; nt < 4; nt++)
        ctx[nt] = __builtin_amdgcn_mfma_f32_16x16x32_bf16(pf, vf[nt],
                                                          ctx[nt], 0, 0, 0);
      lacc = __builtin_amdgcn_mfma_f32_16x16x32_bf16(pf, vones, lacc, 0, 0, 0);
    }
  }

  const size_t obase = (size_t)b * S_ * D_ + (size_t)h * HD_;
  float rinv[4];
#pragma unroll
  for (int r = 0; r < 4; r++) rinv[r] = 1.0f / lacc[r];
#pragma unroll
  for (int nt = 0; nt < 4; nt++)
#pragma unroll
    for (int r = 0; r < 4; r++) {
      const int q = q0 + w * 16 + quad * 4 + r;
      O[obase + (size_t)q * D_ + nt * 16 + tx] =
          __float2bfloat16(ctx[nt][r] * rinv[r]);
    }
}

extern "C" void kernel_launch(void* const* d_in, const int* in_sizes, int n_in,
                              void* d_out, int out_size, void* d_ws, size_t ws_size,
                              hipStream_t stream) {
  const float* x = (const float*)d_in[0];
  const int* mask = (const int*)d_in[1];
  const float* wq = (const float*)d_in[2];
  const float* wk = (const float*)d_in[3];
  const float* wv = (const float*)d_in[4];
  const float* wo = (const float*)d_in[5];
  const float* bo = (const float*)d_in[6];
  const float* ln2s = (const float*)d_in[9];
  const float* ln2b = (const float*)d_in[10];
  const float* w1 = (const float*)d_in[11];
  const float* b1 = (const float*)d_in[12];
  const float* w2 = (const float*)d_in[13];
  const float* b2 = (const float*)d_in[14];
  float* out = (float*)d_out;

  const int M = B_ * S_;  // 4096
  char* ws = (char*)d_ws;
  const size_t MB = (size_t)1 << 20;
  bf16_t* qkv = (bf16_t*)(ws);                 // [0,24M)
  bf16_t* ffn1 = (bf16_t*)(ws);                // [0,32M)
  bf16_t* ctx = (bf16_t*)(ws + 32 * MB);       // 8 MB
  bf16_t* h = (bf16_t*)(ws + 40 * MB);         // 8 MB
  bf16_t* wqkv_t = (bf16_t*)(ws + 48 * MB);    // [3072,1024] = 6 MB
  bf16_t* wo_t = (bf16_t*)(ws + 54 * MB);      // [1024,1024] = 2 MB
  bf16_t* w1_t = (bf16_t*)(ws + 56 * MB);      // [4096,1024] = 8 MB
  bf16_t* w2_t = (bf16_t*)(ws + 64 * MB);      // [1024,4096] = 8 MB
  bf16_t* Pa = (bf16_t*)(ws);                  // step 4: qkv dead, 2x8MB
  bf16_t* Pf = (bf16_t*)(ws + 32 * MB);        // step 7: ctx/h/w*_t dead, 4x8MB
  const size_t slice = (size_t)M * D_;

  // 1. prep: h = LN1(x) + all weight transposes (one launch)
  prep_kernel<<<dim3(16384), 256, 0, stream>>>(x, (const float*)d_in[7],
                                               (const float*)d_in[8], h, wq, wk,
                                               wv, wo, w1, w2, wqkv_t, wo_t,
                                               w1_t, w2_t);

  // 2. qkv = h @ [wq|wk|wv]  (gx=24 n-tiles, gy=32 m-tiles; PM=4,PN=2)
  mgemm_kernel<<<dim3(24 * 32), 256, 0, stream>>>(
      h, wqkv_t, nullptr, qkv, M, 3 * D_, D_, D_, /*Mt=*/8, /*Nt=*/12, /*PM=*/4, 0);

  // 3. ctx = softmax(causal(q k^T)/8) v -> bf16 (MFMA flash, fixed-max)
  fattn_kernel<<<dim3(S_ / 64, H_, B_), 256, 0, stream>>>(qkv, mask, ctx);

  // 4. attn-out split-K x2 (gx=8, gy=32, gz=2; PM=8,PN=1)
  mgemm_kernel<<<dim3(8 * 32 * 2), 256, 0, stream>>>(
      ctx, wo_t, nullptr, Pa, M, D_, D_, D_ / 2, /*Mt=*/4, /*Nt=*/8, /*PM=*/8, 4);

  // 5. out = x + Pa0 + Pa1 + bo ; h = LN2(out)   (fused)
  reduce2_ln_kernel<<<dim3(M), 256, 0, stream>>>(Pa, slice, x, bo, ln2s, ln2b,
                                                 out, h);

  // 6. ffn1 = gelu(h @ w1 + b1)  (gx=32, gy=32; PM=2,PN=4)
  mgemm_kernel<<<dim3(32 * 32), 256, 0, stream>>>(
      h, w1_t, b1, ffn1, M, 4 * D_, D_, D_, /*Mt=*/16, /*Nt=*/8, /*PM=*/2, 1);

  // 7. ffn2 split-K x4 (gx=8, gy=32, gz=4; PM=4,PN=2)
  mgemm_kernel<<<dim3(8 * 32 * 4), 256, 0, stream>>>(
      ffn1, w2_t, nullptr, Pf, M, D_, 4 * D_, D_, /*Mt=*/8, /*Nt=*/4, /*PM=*/4, 4);

  // 8. out = out + sum(Pf) + b2
  reduce4_kernel<<<dim3((size_t)M * D_ / 1024), 256, 0, stream>>>(
      Pf, slice, b2, out, D_);
}